// Round 3
// baseline (183.188 us; speedup 1.0000x reference)
//
#include <hip/hip_runtime.h>
#include <stdint.h>

typedef unsigned short u16;
typedef float f32x4 __attribute__((ext_vector_type(4)));
typedef __bf16 bf16x8 __attribute__((ext_vector_type(8)));
typedef short s16x4 __attribute__((ext_vector_type(4)));

__device__ __forceinline__ u16 f2bf(float f) {
  union { float f; uint32_t u; } c; c.f = f;
  uint32_t u = c.u;
  u += 0x7fffu + ((u >> 16) & 1u);   // RNE
  return (u16)(u >> 16);
}

// pack two fp32 into one dword of 2 bf16 (truncation)
__device__ __forceinline__ uint32_t pkbf(float a, float b) {
  union { float f; uint32_t u; } ua, ub; ua.f = a; ub.f = b;
  return __builtin_amdgcn_perm(ub.u, ua.u, 0x07060302u);
}

// global -> LDS direct copy, 16B per lane. LDS dest = wave-uniform base + lane*16.
#define GLOAD_LDS16(g, l)                                                              \
  __builtin_amdgcn_global_load_lds((__attribute__((address_space(1))) void*)(g),       \
                                   (__attribute__((address_space(3))) void*)(l), 16, 0, 0)

// ---------------------------------------------------------------- fused fp32->bf16
__global__ __launch_bounds__(256) void cvt_all(const float* __restrict__ x,
                                               const float* __restrict__ wq,
                                               const float* __restrict__ wk,
                                               const float* __restrict__ wv,
                                               const float* __restrict__ wo,
                                               u16* __restrict__ xb,
                                               u16* __restrict__ wqkvb,
                                               u16* __restrict__ wob) {
  int bx = blockIdx.x;
  const float* src;
  u16* dst;
  int i;
  if (bx < 4096) {
    src = x; dst = xb; i = bx * 256 + threadIdx.x;
  } else {
    int r = bx - 4096;
    int w = r >> 10;
    i = (r & 1023) * 256 + threadIdx.x;
    if (w == 0)      { src = wq; dst = wqkvb; }
    else if (w == 1) { src = wk; dst = wqkvb + 1048576; }
    else if (w == 2) { src = wv; dst = wqkvb + 2097152; }
    else             { src = wo; dst = wob; }
  }
  const float4 v = ((const float4*)src)[i];
  ushort4 o;
  o.x = f2bf(v.x); o.y = f2bf(v.y); o.z = f2bf(v.z); o.w = f2bf(v.w);
  ((ushort4*)dst)[i] = o;
}

// ---------------------------------------------------------------- QKV projection
// BK=32, rotating 3-buffer, stage issued 2 K-tiles ahead, counted vmcnt (T4).
// C cols 0..1023 -> Q * (0.125*log2e), 1024..2047 -> K; 2048..3071 -> Vt.
__global__ __launch_bounds__(256, 3) void gemm_qkv(const u16* __restrict__ A,
                                                   const u16* __restrict__ B,
                                                   u16* __restrict__ QKb,
                                                   u16* __restrict__ Vt) {
  const int K = 1024;
  __shared__ __align__(16) u16 sA[3 * 4096];   // 3 bufs x [128 rows][32] swizzled
  __shared__ __align__(16) u16 sB[3 * 4096];
  const int tid = threadIdx.x;
  const int lane = tid & 63;
  const int wave = tid >> 6;
  const int quad = lane >> 4, l16 = lane & 15;
  const int wm = (wave >> 1) * 64, wn = (wave & 1) * 64;
  const int bm = blockIdx.y * 128, bn = blockIdx.x * 128;

  f32x4 acc[4][4];
#pragma unroll
  for (int i = 0; i < 4; i++)
#pragma unroll
    for (int j = 0; j < 4; j++) acc[i][j] = (f32x4){0.f, 0.f, 0.f, 0.f};

#define QKV_STAGE(t, bi)                                                           \
  {                                                                                \
    const int k0s = (t) * 32;                                                      \
    char* dA = (char*)(sA + (bi) * 4096);                                          \
    char* dB = (char*)(sB + (bi) * 4096);                                          \
    _Pragma("unroll")                                                              \
    for (int k2 = 0; k2 < 2; k2++) {                                               \
      int u = k2 * 256 + tid;                                                      \
      int row = u >> 2, c4 = (u & 3) ^ (row & 3);                                  \
      GLOAD_LDS16(A + (size_t)(bm + row) * K + k0s + c4 * 8, dA + u * 16);         \
      GLOAD_LDS16(B + (size_t)(bn + row) * K + k0s + c4 * 8, dB + u * 16);         \
    }                                                                              \
  }

  QKV_STAGE(0, 0);
  QKV_STAGE(1, 1);

  int cur = 0, stg = 2;
  for (int T = 0; T < 32; ++T) {
    if (T < 31) asm volatile("s_waitcnt vmcnt(4)" ::: "memory");
    else        asm volatile("s_waitcnt vmcnt(0)" ::: "memory");
    __builtin_amdgcn_s_barrier();
    asm volatile("" ::: "memory");
    if (T < 30) QKV_STAGE(T + 2, stg);

    const u16* cA = sA + cur * 4096;
    const u16* cB = sB + cur * 4096;
    bf16x8 af[4], bfr[4];
#pragma unroll
    for (int mt = 0; mt < 4; mt++) {
      int ra = wm + mt * 16 + l16;
      af[mt] = *(const bf16x8*)&cA[ra * 32 + ((quad ^ (ra & 3)) * 8)];
    }
#pragma unroll
    for (int nt = 0; nt < 4; nt++) {
      int rb = wn + nt * 16 + l16;
      bfr[nt] = *(const bf16x8*)&cB[rb * 32 + ((quad ^ (rb & 3)) * 8)];
    }
#pragma unroll
    for (int mt = 0; mt < 4; mt++)
#pragma unroll
      for (int nt = 0; nt < 4; nt++)
        acc[mt][nt] = __builtin_amdgcn_mfma_f32_16x16x32_bf16(af[mt], bfr[nt], acc[mt][nt], 0, 0, 0);

    cur = (cur == 2) ? 0 : cur + 1;
    stg = (stg == 2) ? 0 : stg + 1;
  }
#undef QKV_STAGE

  if (blockIdx.x < 16) {
    const float qs = (blockIdx.x < 8) ? 0.18033688011f : 1.0f;
#pragma unroll
    for (int mt = 0; mt < 4; mt++)
#pragma unroll
      for (int nt = 0; nt < 4; nt++)
#pragma unroll
        for (int r = 0; r < 4; r++) {
          int row = bm + wm + mt * 16 + quad * 4 + r;
          int col = bn + wn + nt * 16 + l16;
          QKb[(size_t)row * 2048 + col] = f2bf(acc[mt][nt][r] * qs);
        }
  } else {
#pragma unroll
    for (int mt = 0; mt < 4; mt++)
#pragma unroll
      for (int nt = 0; nt < 4; nt++) {
        int hd = (bn - 2048) + wn + nt * 16 + l16;
        int tok = bm + wm + mt * 16 + quad * 4;
        ushort4 o;
        o.x = f2bf(acc[mt][nt][0]);
        o.y = f2bf(acc[mt][nt][1]);
        o.z = f2bf(acc[mt][nt][2]);
        o.w = f2bf(acc[mt][nt][3]);
        *(ushort4*)&Vt[(size_t)hd * 4096 + tok] = o;
      }
  }
}

// ---------------------------------------------------------------- flash attention
// KV-SPLIT: 4 waves split over kv (16 rows each of the 64-row tile), each wave
// computes partial O for ALL 128 q rows. Kills the 4x LDS fragment duplication
// (64KB -> 16KB reads per block-iter): round-2 counters showed both pipes ~40%
// with the LDS pipe the critical path. Rotating 3-buffer K/V + counted vmcnt
// kept. Epilogue: cross-wave O reduce through two 32KB LDS regions.
__global__ __launch_bounds__(256, 2) void attn_fwd(const u16* __restrict__ QKb,
                                                   const u16* __restrict__ Vt,
                                                   u16* __restrict__ O) {
  const int bx = blockIdx.x;
  const int qt = bx >> 5;         // 0..15 (BQ=128)
  const int h  = (bx >> 1) & 15;
  const int b  = bx & 1;
  const int tid = threadIdx.x;    // 0..255
  const int lane = tid & 63;
  const int wave = tid >> 6;      // 0..3 = kv-slice owner
  const int quad = lane >> 4, l16 = lane & 15;

  // 64 KB: sQ[128x64] | sK 3x[64x64] | sV 3x[64x64]; epilogue reuses all of it.
  __shared__ __align__(16) u16 smem[32768];
  u16* sQ = smem;                       // 8192 u16 (16 KB)
  u16* sK = smem + 8192;                // 3 * 4096
  u16* sV = smem + 20480;               // 3 * 4096
  float* R0 = (float*)smem;             // epilogue: bytes [0, 32K)
  float* R1 = (float*)(smem + 16384);   // epilogue: bytes [32K, 64K)
  float* lsumT = (float*)smem;          // epilogue: first 2 KB (before R0 use)

  const int tok0 = b * 2048;
  const int q0 = qt * 128;
  const int colh = h * 64;

  // ---- prologue stages: Q (4 loads/thread), then K/V tiles 0 and 1 (8 loads)
#pragma unroll
  for (int k2 = 0; k2 < 4; k2++) {
    int c = k2 * 256 + tid;
    int row = c >> 3, c8 = (c & 7) ^ (row & 7);
    GLOAD_LDS16(QKb + (size_t)(tok0 + q0 + row) * 2048 + colh + c8 * 8,
                (char*)sQ + c * 16);
  }
#pragma unroll
  for (int t = 0; t < 2; t++) {
#pragma unroll
    for (int k2 = 0; k2 < 2; k2++) {
      int c = k2 * 256 + tid;
      int row = c >> 3, c8 = (c & 7) ^ (row & 7);
      GLOAD_LDS16(QKb + (size_t)(tok0 + t * 64 + row) * 2048 + 1024 + colh + c8 * 8,
                  (char*)(sK + t * 4096) + c * 16);
      GLOAD_LDS16(Vt + (size_t)(colh + row) * 4096 + tok0 + t * 64 + c8 * 8,
                  (char*)(sV + t * 4096) + c * 16);
    }
  }
  // land Q (leave K0,V0,K1,V1 = 8 loads in flight)
  asm volatile("s_waitcnt vmcnt(8)" ::: "memory");
  __builtin_amdgcn_s_barrier();
  asm volatile("" ::: "memory");

  // ---- hoist ALL 128 q rows as B-op fragments (8 subs of 16 rows) — every
  // wave holds full Q (64 VGPR); kv-split means each wave needs all q.
  bf16x8 aq[8][2];
#pragma unroll
  for (int sub = 0; sub < 8; sub++)
#pragma unroll
    for (int kh = 0; kh < 2; kh++) {
      int rq = sub * 16 + l16;
      aq[sub][kh] = *(const bf16x8*)&sQ[rq * 64 + (((kh * 4 + quad) ^ (rq & 7)) * 8)];
    }

  f32x4 oacc[8][4];                // partial O^T: [q=sub*16+l16][d=db*16+quad*4+r]
  float lsum[8];
#pragma unroll
  for (int sub = 0; sub < 8; sub++) {
    lsum[sub] = 0.f;
#pragma unroll
    for (int db = 0; db < 4; db++) oacc[sub][db] = (f32x4){0.f, 0.f, 0.f, 0.f};
  }

  int cur = 0, stg = 2;
  for (int it = 0; it < 32; ++it) {
    if (it < 31) asm volatile("s_waitcnt vmcnt(4)" ::: "memory");
    else         asm volatile("s_waitcnt vmcnt(0)" ::: "memory");
    __builtin_amdgcn_s_barrier();
    asm volatile("" ::: "memory");
    if (it < 30) {
      const int nkv = (it + 2) * 64;
      char* sKn = (char*)(sK + stg * 4096);
      char* sVn = (char*)(sV + stg * 4096);
#pragma unroll
      for (int k2 = 0; k2 < 2; k2++) {
        int c = k2 * 256 + tid;
        int row = c >> 3, c8 = (c & 7) ^ (row & 7);
        GLOAD_LDS16(QKb + (size_t)(tok0 + nkv + row) * 2048 + 1024 + colh + c8 * 8,
                    sKn + c * 16);
        GLOAD_LDS16(Vt + (size_t)(colh + row) * 4096 + tok0 + nkv + c8 * 8,
                    sVn + c * 16);
      }
    }
    const u16* sKc = sK + cur * 4096;
    const u16* sVc = sV + cur * 4096;

    // K fragment: ONLY this wave's 16 kv rows (2 b128 reads vs 8 before)
    bf16x8 kf[2];
#pragma unroll
    for (int kh = 0; kh < 2; kh++) {
      int rr = wave * 16 + l16;
      kf[kh] = *(const bf16x8*)&sKc[rr * 64 + (((kh * 4 + quad) ^ (rr & 7)) * 8)];
    }
    // V fragment: this wave's 16 kv cols x full d (4 b64 reads vs 16 before)
    s16x4 vf[4];
#pragma unroll
    for (int db = 0; db < 4; db++) {
      int row = db * 16 + l16;
      int c16 = (wave * 2 + (quad >> 1)) ^ (row & 7);
      vf[db] = *(const s16x4*)&sVc[row * 64 + c16 * 8 + (quad & 1) * 4];
    }

#pragma unroll
    for (int sub = 0; sub < 8; sub++) {
      // S^T = K Q^T : C rows = kv (wave*16+quad*4+r), cols = q (sub*16+l16)
      f32x4 c = (f32x4){0.f, 0.f, 0.f, 0.f};
      c = __builtin_amdgcn_mfma_f32_16x16x32_bf16(kf[0], aq[sub][0], c, 0, 0, 0);
      c = __builtin_amdgcn_mfma_f32_16x16x32_bf16(kf[1], aq[sub][1], c, 0, 0, 0);
      float e0 = __builtin_amdgcn_exp2f(c[0]);
      float e1 = __builtin_amdgcn_exp2f(c[1]);
      float e2 = __builtin_amdgcn_exp2f(c[2]);
      float e3 = __builtin_amdgcn_exp2f(c[3]);
      lsum[sub] += (e0 + e1) + (e2 + e3);
      union { uint32_t u[2]; s16x4 v; } bb;
      bb.u[0] = pkbf(e0, e1);
      bb.u[1] = pkbf(e2, e3);
#pragma unroll
      for (int db = 0; db < 4; db++)
        oacc[sub][db] = __builtin_amdgcn_mfma_f32_16x16x16bf16_1k(vf[db], bb.v, oacc[sub][db], 0, 0, 0);
    }
    cur = (cur == 2) ? 0 : cur + 1;
    stg = (stg == 2) ? 0 : stg + 1;
  }

  // ---- epilogue: cross-wave reduction of partial O and lsum
  asm volatile("s_waitcnt lgkmcnt(0)" ::: "memory");
  __builtin_amdgcn_s_barrier();         // all loop LDS reads retired

  // quad-reduce lsum (each lane then holds this wave's kv-partial for q=sub*16+l16)
#pragma unroll
  for (int sub = 0; sub < 8; sub++) {
    float v = lsum[sub];
    v += __shfl_xor(v, 16, 64);
    v += __shfl_xor(v, 32, 64);
    lsum[sub] = v;
  }
  if (quad == 0) {
#pragma unroll
    for (int sub = 0; sub < 8; sub++)
      lsumT[wave * 128 + sub * 16 + l16] = lsum[sub];
  }
  __builtin_amdgcn_s_barrier();
  // each wave owns output subs {2*wave, 2*wave+1}; 1/total for its q rows
  float rtot[2];
#pragma unroll
  for (int j = 0; j < 2; j++) {
    int so = wave * 2 + j;
    float t = lsumT[0 * 128 + so * 16 + l16] + lsumT[1 * 128 + so * 16 + l16] +
              lsumT[2 * 128 + so * 16 + l16] + lsumT[3 * 128 + so * 16 + l16];
    rtot[j] = 1.0f / t;
  }
  __builtin_amdgcn_s_barrier();         // lsumT reads done before R0 overwrite

  // phase A: waves 0,1 write full partial [128q][64d] f32 (XOR-swizzled d)
  if (wave < 2) {
    float* R = wave ? R1 : R0;
#pragma unroll
    for (int sub = 0; sub < 8; sub++)
#pragma unroll
      for (int db = 0; db < 4; db++) {
        int q = sub * 16 + l16;
        int d = db * 16 + quad * 4;
        *(f32x4*)&R[q * 64 + (d ^ ((q & 7) << 3))] = oacc[sub][db];
      }
  }
  __builtin_amdgcn_s_barrier();
  // phase B: waves 2,3 accumulate into R0/R1
  if (wave >= 2) {
    float* R = (wave == 3) ? R1 : R0;
#pragma unroll
    for (int sub = 0; sub < 8; sub++)
#pragma unroll
      for (int db = 0; db < 4; db++) {
        int q = sub * 16 + l16;
        int d = db * 16 + quad * 4;
        float* p = &R[q * 64 + (d ^ ((q & 7) << 3))];
        *(f32x4*)p = *(const f32x4*)p + oacc[sub][db];
      }
  }
  __builtin_amdgcn_s_barrier();
  // phase C: wave w outputs q rows of subs {2w, 2w+1}: O = (R0+R1) * 1/lsum
#pragma unroll
  for (int j = 0; j < 2; j++) {
    int sub = wave * 2 + j;
    int q = sub * 16 + l16;
#pragma unroll
    for (int db = 0; db < 4; db++) {
      int d = db * 16 + quad * 4;
      int loc = q * 64 + (d ^ ((q & 7) << 3));
      f32x4 o = *(const f32x4*)&R0[loc] + *(const f32x4*)&R1[loc];
      ushort4 st;
      st.x = f2bf(o[0] * rtot[j]);
      st.y = f2bf(o[1] * rtot[j]);
      st.z = f2bf(o[2] * rtot[j]);
      st.w = f2bf(o[3] * rtot[j]);
      *(ushort4*)&O[(size_t)(tok0 + q0 + q) * 1024 + colh + d] = st;
    }
  }
}

// ---------------------------------------------------------------- final projection
// 128x64 tiles, BK=32, rotating 3-buffer + counted vmcnt (same scheme as qkv).
__global__ __launch_bounds__(256) void gemm_out(const u16* __restrict__ A,
                                                const u16* __restrict__ B,
                                                float* __restrict__ C) {
  const int N = 1024, K = 1024;
  __shared__ __align__(16) u16 sA[3 * 4096];   // 3 x [128][32]
  __shared__ __align__(16) u16 sB[3 * 2048];   // 3 x [64][32]
  const int tid = threadIdx.x;
  const int lane = tid & 63;
  const int wave = tid >> 6;
  const int quad = lane >> 4, l16 = lane & 15;
  const int wm = (wave >> 1) * 64, wn = (wave & 1) * 32;
  const int bm = blockIdx.y * 128, bn = blockIdx.x * 64;

  f32x4 acc[4][2];
#pragma unroll
  for (int i = 0; i < 4; i++)
#pragma unroll
    for (int j = 0; j < 2; j++) acc[i][j] = (f32x4){0.f, 0.f, 0.f, 0.f};

#define OUT_STAGE(t, bi)                                                           \
  {                                                                                \
    const int k0s = (t) * 32;                                                      \
    char* dA = (char*)(sA + (bi) * 4096);                                          \
    char* dB = (char*)(sB + (bi) * 2048);                                          \
    _Pragma("unroll")                                                              \
    for (int k2 = 0; k2 < 2; k2++) {                                               \
      int u = k2 * 256 + tid;                                                      \
      int row = u >> 2, c4 = (u & 3) ^ (row & 3);                                  \
      GLOAD_LDS16(A + (size_t)(bm + row) * K + k0s + c4 * 8, dA + u * 16);         \
    }                                                                              \
    {                                                                              \
      int u = tid;                                                                 \
      int row = u >> 2, c4 = (u & 3) ^ (row & 3);                                  \
      GLOAD_LDS16(B + (size_t)(bn + row) * K + k0s + c4 * 8, dB + u * 16);         \
    }                                                                              \
  }

  OUT_STAGE(0, 0);
  OUT_STAGE(1, 1);

  int cur = 0, stg = 2;
  for (int T = 0; T < 32; ++T) {
    if (T < 31) asm volatile("s_waitcnt vmcnt(3)" ::: "memory");
    else        asm volatile("s_waitcnt vmcnt(0)" ::: "memory");
    __builtin_amdgcn_s_barrier();
    asm volatile("" ::: "memory");
    if (T < 30) OUT_STAGE(T + 2, stg);

    const u16* cA = sA + cur * 4096;
    const u16* cB = sB + cur * 2048;
    bf16x8 af[4], bfr[2];
#pragma unroll
    for (int mt = 0; mt < 4; mt++) {
      int ra = wm + mt * 16 + l16;
      af[mt] = *(const bf16x8*)&cA[ra * 32 + ((quad ^ (ra & 3)) * 8)];
    }
#pragma unroll
    for (int nt = 0; nt < 2; nt++) {
      int rb = wn + nt * 16 + l16;
      bfr[nt] = *(const bf16x8*)&cB[rb * 32 + ((quad ^ (rb & 3)) * 8)];
    }
#pragma unroll
    for (int mt = 0; mt < 4; mt++)
#pragma unroll
      for (int nt = 0; nt < 2; nt++)
        acc[mt][nt] = __builtin_amdgcn_mfma_f32_16x16x32_bf16(af[mt], bfr[nt], acc[mt][nt], 0, 0, 0);

    cur = (cur == 2) ? 0 : cur + 1;
    stg = (stg == 2) ? 0 : stg + 1;
  }
#undef OUT_STAGE

#pragma unroll
  for (int mt = 0; mt < 4; mt++)
#pragma unroll
    for (int nt = 0; nt < 2; nt++)
#pragma unroll
      for (int r = 0; r < 4; r++) {
        int row = bm + wm + mt * 16 + quad * 4 + r;
        int col = bn + wn + nt * 16 + l16;
        C[(size_t)row * N + col] = acc[mt][nt][r];
      }
}

// ---------------------------------------------------------------- launch
extern "C" void kernel_launch(void* const* d_in, const int* in_sizes, int n_in,
                              void* d_out, int out_size, void* d_ws, size_t ws_size,
                              hipStream_t stream) {
  const float* x  = (const float*)d_in[0];
  const float* wq = (const float*)d_in[1];
  const float* wk = (const float*)d_in[2];
  const float* wv = (const float*)d_in[3];
  const float* wo = (const float*)d_in[4];
  float* out = (float*)d_out;
  char* ws = (char*)d_ws;
  const size_t MB = 1u << 20;

  u16* xb    = (u16*)(ws);            // 8 MB  [4096 x 1024] bf16 x
  u16* wqkvb = (u16*)(ws + 8 * MB);   // 6 MB  [3072 x 1024]
  u16* wob   = (u16*)(ws + 14 * MB);  // 2 MB
  u16* QKb   = (u16*)(ws + 16 * MB);  // 16 MB [4096 x 2048] (Q*s | K)
  u16* Vtb   = (u16*)(ws + 32 * MB);  // 8 MB  [1024 hd x 4096 tok]
  u16* Ob    = xb;                    // alias: x dead after QKV gemm

  cvt_all<<<8192, 256, 0, stream>>>(x, wq, wk, wv, wo, xb, wqkvb, wob);

  gemm_qkv<<<dim3(24, 32), 256, 0, stream>>>(xb, wqkvb, QKb, Vtb);

  attn_fwd<<<512, 256, 0, stream>>>(QKb, Vtb, Ob);

  gemm_out<<<dim3(16, 32), 256, 0, stream>>>(Ob, wob, out);
}

// Round 4
// 179.442 us; speedup vs baseline: 1.0209x; 1.0209x over previous
//
#include <hip/hip_runtime.h>
#include <stdint.h>

typedef unsigned short u16;
typedef float f32x4 __attribute__((ext_vector_type(4)));
typedef __bf16 bf16x8 __attribute__((ext_vector_type(8)));
typedef short s16x4 __attribute__((ext_vector_type(4)));

__device__ __forceinline__ u16 f2bf(float f) {
  union { float f; uint32_t u; } c; c.f = f;
  uint32_t u = c.u;
  u += 0x7fffu + ((u >> 16) & 1u);   // RNE
  return (u16)(u >> 16);
}

// pack two fp32 into one dword of 2 bf16 (truncation)
__device__ __forceinline__ uint32_t pkbf(float a, float b) {
  union { float f; uint32_t u; } ua, ub; ua.f = a; ub.f = b;
  return __builtin_amdgcn_perm(ub.u, ua.u, 0x07060302u);
}

// global -> LDS direct copy, 16B per lane. LDS dest = wave-uniform base + lane*16.
#define GLOAD_LDS16(g, l)                                                              \
  __builtin_amdgcn_global_load_lds((__attribute__((address_space(1))) void*)(g),       \
                                   (__attribute__((address_space(3))) void*)(l), 16, 0, 0)

// ---------------------------------------------------------------- fused fp32->bf16
__global__ __launch_bounds__(256) void cvt_all(const float* __restrict__ x,
                                               const float* __restrict__ wq,
                                               const float* __restrict__ wk,
                                               const float* __restrict__ wv,
                                               const float* __restrict__ wo,
                                               u16* __restrict__ xb,
                                               u16* __restrict__ wqkvb,
                                               u16* __restrict__ wob) {
  int bx = blockIdx.x;
  const float* src;
  u16* dst;
  int i;
  if (bx < 4096) {
    src = x; dst = xb; i = bx * 256 + threadIdx.x;
  } else {
    int r = bx - 4096;
    int w = r >> 10;
    i = (r & 1023) * 256 + threadIdx.x;
    if (w == 0)      { src = wq; dst = wqkvb; }
    else if (w == 1) { src = wk; dst = wqkvb + 1048576; }
    else if (w == 2) { src = wv; dst = wqkvb + 2097152; }
    else             { src = wo; dst = wob; }
  }
  const float4 v = ((const float4*)src)[i];
  ushort4 o;
  o.x = f2bf(v.x); o.y = f2bf(v.y); o.z = f2bf(v.z); o.w = f2bf(v.w);
  ((ushort4*)dst)[i] = o;
}

// ---------------------------------------------------------------- QKV projection
// BK=32, rotating 3-buffer, stage issued 2 K-tiles ahead, counted vmcnt (T4).
// C cols 0..1023 -> Q * (0.125*log2e), 1024..2047 -> K; 2048..3071 -> Vt.
__global__ __launch_bounds__(256, 3) void gemm_qkv(const u16* __restrict__ A,
                                                   const u16* __restrict__ B,
                                                   u16* __restrict__ QKb,
                                                   u16* __restrict__ Vt) {
  const int K = 1024;
  __shared__ __align__(16) u16 sA[3 * 4096];   // 3 bufs x [128 rows][32] swizzled
  __shared__ __align__(16) u16 sB[3 * 4096];
  const int tid = threadIdx.x;
  const int lane = tid & 63;
  const int wave = tid >> 6;
  const int quad = lane >> 4, l16 = lane & 15;
  const int wm = (wave >> 1) * 64, wn = (wave & 1) * 64;
  const int bm = blockIdx.y * 128, bn = blockIdx.x * 128;

  f32x4 acc[4][4];
#pragma unroll
  for (int i = 0; i < 4; i++)
#pragma unroll
    for (int j = 0; j < 4; j++) acc[i][j] = (f32x4){0.f, 0.f, 0.f, 0.f};

#define QKV_STAGE(t, bi)                                                           \
  {                                                                                \
    const int k0s = (t) * 32;                                                      \
    char* dA = (char*)(sA + (bi) * 4096);                                          \
    char* dB = (char*)(sB + (bi) * 4096);                                          \
    _Pragma("unroll")                                                              \
    for (int k2 = 0; k2 < 2; k2++) {                                               \
      int u = k2 * 256 + tid;                                                      \
      int row = u >> 2, c4 = (u & 3) ^ (row & 3);                                  \
      GLOAD_LDS16(A + (size_t)(bm + row) * K + k0s + c4 * 8, dA + u * 16);         \
      GLOAD_LDS16(B + (size_t)(bn + row) * K + k0s + c4 * 8, dB + u * 16);         \
    }                                                                              \
  }

  QKV_STAGE(0, 0);
  QKV_STAGE(1, 1);

  int cur = 0, stg = 2;
  for (int T = 0; T < 32; ++T) {
    if (T < 31) asm volatile("s_waitcnt vmcnt(4)" ::: "memory");
    else        asm volatile("s_waitcnt vmcnt(0)" ::: "memory");
    __builtin_amdgcn_s_barrier();
    asm volatile("" ::: "memory");
    if (T < 30) QKV_STAGE(T + 2, stg);

    const u16* cA = sA + cur * 4096;
    const u16* cB = sB + cur * 4096;
    bf16x8 af[4], bfr[4];
#pragma unroll
    for (int mt = 0; mt < 4; mt++) {
      int ra = wm + mt * 16 + l16;
      af[mt] = *(const bf16x8*)&cA[ra * 32 + ((quad ^ (ra & 3)) * 8)];
    }
#pragma unroll
    for (int nt = 0; nt < 4; nt++) {
      int rb = wn + nt * 16 + l16;
      bfr[nt] = *(const bf16x8*)&cB[rb * 32 + ((quad ^ (rb & 3)) * 8)];
    }
#pragma unroll
    for (int mt = 0; mt < 4; mt++)
#pragma unroll
      for (int nt = 0; nt < 4; nt++)
        acc[mt][nt] = __builtin_amdgcn_mfma_f32_16x16x32_bf16(af[mt], bfr[nt], acc[mt][nt], 0, 0, 0);

    cur = (cur == 2) ? 0 : cur + 1;
    stg = (stg == 2) ? 0 : stg + 1;
  }
#undef QKV_STAGE

  if (blockIdx.x < 16) {
    const float qs = (blockIdx.x < 8) ? 0.18033688011f : 1.0f;
#pragma unroll
    for (int mt = 0; mt < 4; mt++)
#pragma unroll
      for (int nt = 0; nt < 4; nt++)
#pragma unroll
        for (int r = 0; r < 4; r++) {
          int row = bm + wm + mt * 16 + quad * 4 + r;
          int col = bn + wn + nt * 16 + l16;
          QKb[(size_t)row * 2048 + col] = f2bf(acc[mt][nt][r] * qs);
        }
  } else {
#pragma unroll
    for (int mt = 0; mt < 4; mt++)
#pragma unroll
      for (int nt = 0; nt < 4; nt++) {
        int hd = (bn - 2048) + wn + nt * 16 + l16;
        int tok = bm + wm + mt * 16 + quad * 4;
        ushort4 o;
        o.x = f2bf(acc[mt][nt][0]);
        o.y = f2bf(acc[mt][nt][1]);
        o.z = f2bf(acc[mt][nt][2]);
        o.w = f2bf(acc[mt][nt][3]);
        *(ushort4*)&Vt[(size_t)hd * 4096 + tok] = o;
      }
  }
}

// ---------------------------------------------------------------- flash attention
// HYBRID 2x2 SPLIT: wave = (q-group = wave>>1) x (kv-half = wave&1).
// Each wave: 64 q rows x 32 kv rows -> per-iter LDS tile traffic 2x (vs 4x in
// the round-2 q-split) at ~150 VGPR (round-3's full kv-split hit 128-VGPR cap
// and spilled: WRITE_SIZE +6MB, MfmaUtil -5). Rotating 3-buffer + counted
// vmcnt kept. Epilogue: pairwise O reduction through 2x16KB LDS regions.
__global__ __launch_bounds__(256, 2) void attn_fwd(const u16* __restrict__ QKb,
                                                   const u16* __restrict__ Vt,
                                                   u16* __restrict__ O) {
  const int bx = blockIdx.x;
  const int qt = bx >> 5;         // 0..15 (BQ=128)
  const int h  = (bx >> 1) & 15;
  const int b  = bx & 1;
  const int tid = threadIdx.x;    // 0..255
  const int lane = tid & 63;
  const int wave = tid >> 6;      // 0..3
  const int wq = wave >> 1;       // q group: rows wq*64 .. wq*64+63
  const int wk = wave & 1;        // kv half: rows wk*32 .. wk*32+31
  const int quad = lane >> 4, l16 = lane & 15;

  // 64 KB: sQ[128x64] | sK 3x[64x64] | sV 3x[64x64]; epilogue reuses bytes 0..33K.
  __shared__ __align__(16) u16 smem[32768];
  u16* sQ = smem;                 // 8192 u16 (16 KB)
  u16* sK = smem + 8192;          // 3 * 4096
  u16* sV = smem + 20480;         // 3 * 4096

  const int tok0 = b * 2048;
  const int q0 = qt * 128;
  const int colh = h * 64;

  // ---- prologue stages: Q (4 loads/thread), then K/V tiles 0 and 1 (8 loads)
#pragma unroll
  for (int k2 = 0; k2 < 4; k2++) {
    int c = k2 * 256 + tid;
    int row = c >> 3, c8 = (c & 7) ^ (row & 7);
    GLOAD_LDS16(QKb + (size_t)(tok0 + q0 + row) * 2048 + colh + c8 * 8,
                (char*)sQ + c * 16);
  }
#pragma unroll
  for (int t = 0; t < 2; t++) {
#pragma unroll
    for (int k2 = 0; k2 < 2; k2++) {
      int c = k2 * 256 + tid;
      int row = c >> 3, c8 = (c & 7) ^ (row & 7);
      GLOAD_LDS16(QKb + (size_t)(tok0 + t * 64 + row) * 2048 + 1024 + colh + c8 * 8,
                  (char*)(sK + t * 4096) + c * 16);
      GLOAD_LDS16(Vt + (size_t)(colh + row) * 4096 + tok0 + t * 64 + c8 * 8,
                  (char*)(sV + t * 4096) + c * 16);
    }
  }
  // land Q (leave K0,V0,K1,V1 = 8 loads in flight)
  asm volatile("s_waitcnt vmcnt(8)" ::: "memory");
  __builtin_amdgcn_s_barrier();
  asm volatile("" ::: "memory");

  // ---- hoist this q-group's 64 q rows as B-op fragments (4 subs of 16)
  bf16x8 aq[4][2];
#pragma unroll
  for (int sub = 0; sub < 4; sub++)
#pragma unroll
    for (int kh = 0; kh < 2; kh++) {
      int rq = wq * 64 + sub * 16 + l16;
      aq[sub][kh] = *(const bf16x8*)&sQ[rq * 64 + (((kh * 4 + quad) ^ (rq & 7)) * 8)];
    }

  f32x4 oacc[4][4];   // partial O^T over this wave's kv half: [q=sub*16+l16][d]
  float lsum[4];
#pragma unroll
  for (int sub = 0; sub < 4; sub++) {
    lsum[sub] = 0.f;
#pragma unroll
    for (int db = 0; db < 4; db++) oacc[sub][db] = (f32x4){0.f, 0.f, 0.f, 0.f};
  }

  int cur = 0, stg = 2;
  for (int it = 0; it < 32; ++it) {
    if (it < 31) asm volatile("s_waitcnt vmcnt(4)" ::: "memory");
    else         asm volatile("s_waitcnt vmcnt(0)" ::: "memory");
    __builtin_amdgcn_s_barrier();
    asm volatile("" ::: "memory");
    if (it < 30) {
      const int nkv = (it + 2) * 64;
      char* sKn = (char*)(sK + stg * 4096);
      char* sVn = (char*)(sV + stg * 4096);
#pragma unroll
      for (int k2 = 0; k2 < 2; k2++) {
        int c = k2 * 256 + tid;
        int row = c >> 3, c8 = (c & 7) ^ (row & 7);
        GLOAD_LDS16(QKb + (size_t)(tok0 + nkv + row) * 2048 + 1024 + colh + c8 * 8,
                    sKn + c * 16);
        GLOAD_LDS16(Vt + (size_t)(colh + row) * 4096 + tok0 + nkv + c8 * 8,
                    sVn + c * 16);
      }
    }
    const u16* sKc = sK + cur * 4096;
    const u16* sVc = sV + cur * 4096;

    // K fragments: this wave's 32 kv rows (4 b128 reads)
    bf16x8 kf[2][2];
#pragma unroll
    for (int nt = 0; nt < 2; nt++)
#pragma unroll
      for (int kh = 0; kh < 2; kh++) {
        int rr = wk * 32 + nt * 16 + l16;
        kf[nt][kh] = *(const bf16x8*)&sKc[rr * 64 + (((kh * 4 + quad) ^ (rr & 7)) * 8)];
      }
    // V fragments: this wave's 32 kv cols x full d (8 b64 reads)
    s16x4 vf[4][2];
#pragma unroll
    for (int db = 0; db < 4; db++)
#pragma unroll
      for (int nt = 0; nt < 2; nt++) {
        int row = db * 16 + l16;
        int c16 = ((wk * 2 + nt) * 2 + (quad >> 1)) ^ (row & 7);
        vf[db][nt] = *(const s16x4*)&sVc[row * 64 + c16 * 8 + (quad & 1) * 4];
      }

#pragma unroll
    for (int sub = 0; sub < 4; sub++) {
      // S^T = K Q^T : C rows = kv (wk*32+nt*16+quad*4+r), cols = q (sub*16+l16)
#pragma unroll
      for (int nt = 0; nt < 2; nt++) {
        f32x4 c = (f32x4){0.f, 0.f, 0.f, 0.f};
        c = __builtin_amdgcn_mfma_f32_16x16x32_bf16(kf[nt][0], aq[sub][0], c, 0, 0, 0);
        c = __builtin_amdgcn_mfma_f32_16x16x32_bf16(kf[nt][1], aq[sub][1], c, 0, 0, 0);
        float e0 = __builtin_amdgcn_exp2f(c[0]);
        float e1 = __builtin_amdgcn_exp2f(c[1]);
        float e2 = __builtin_amdgcn_exp2f(c[2]);
        float e3 = __builtin_amdgcn_exp2f(c[3]);
        lsum[sub] += (e0 + e1) + (e2 + e3);
        union { uint32_t u[2]; s16x4 v; } bb;
        bb.u[0] = pkbf(e0, e1);
        bb.u[1] = pkbf(e2, e3);
#pragma unroll
        for (int db = 0; db < 4; db++)
          oacc[sub][db] = __builtin_amdgcn_mfma_f32_16x16x16bf16_1k(vf[db][nt], bb.v, oacc[sub][db], 0, 0, 0);
      }
    }
    cur = (cur == 2) ? 0 : cur + 1;
    stg = (stg == 2) ? 0 : stg + 1;
  }

  // ---- epilogue: pairwise cross-wave reduction (wk=0 writes, wk=1 combines)
  asm volatile("s_waitcnt lgkmcnt(0)" ::: "memory");
  __builtin_amdgcn_s_barrier();         // all loop LDS reads retired

  // quad-reduce lsum: lane then holds this wave's 32-kv-row sum for q=sub*16+l16
#pragma unroll
  for (int sub = 0; sub < 4; sub++) {
    float v = lsum[sub];
    v += __shfl_xor(v, 16, 64);
    v += __shfl_xor(v, 32, 64);
    lsum[sub] = v;
  }

  float* Rbase = (float*)((char*)smem + wq * 16384);   // [64 q][64 d] f32, swizzled
  float* lsumT = (float*)((char*)smem + 32768);        // 128 floats

  if (wk == 0) {
#pragma unroll
    for (int sub = 0; sub < 4; sub++) {
#pragma unroll
      for (int db = 0; db < 4; db++) {
        int q = sub * 16 + l16;
        int d = db * 16 + quad * 4;
        *(f32x4*)&Rbase[q * 64 + (d ^ ((q & 7) << 3))] = oacc[sub][db];
      }
      if (quad == 0) lsumT[wq * 64 + sub * 16 + l16] = lsum[sub];
    }
  }
  __builtin_amdgcn_s_barrier();
  if (wk == 1) {
#pragma unroll
    for (int sub = 0; sub < 4; sub++) {
      int q = sub * 16 + l16;
      float rt = 1.0f / (lsum[sub] + lsumT[wq * 64 + q]);
#pragma unroll
      for (int db = 0; db < 4; db++) {
        int d = db * 16 + quad * 4;
        f32x4 o = *(const f32x4*)&Rbase[q * 64 + (d ^ ((q & 7) << 3))] + oacc[sub][db];
        ushort4 st;
        st.x = f2bf(o[0] * rt);
        st.y = f2bf(o[1] * rt);
        st.z = f2bf(o[2] * rt);
        st.w = f2bf(o[3] * rt);
        *(ushort4*)&O[(size_t)(tok0 + q0 + wq * 64 + q) * 1024 + colh + d] = st;
      }
    }
  }
}

// ---------------------------------------------------------------- final projection
// 128x64 tiles, BK=32, rotating 3-buffer + counted vmcnt (same scheme as qkv).
__global__ __launch_bounds__(256) void gemm_out(const u16* __restrict__ A,
                                                const u16* __restrict__ B,
                                                float* __restrict__ C) {
  const int N = 1024, K = 1024;
  __shared__ __align__(16) u16 sA[3 * 4096];   // 3 x [128][32]
  __shared__ __align__(16) u16 sB[3 * 2048];   // 3 x [64][32]
  const int tid = threadIdx.x;
  const int lane = tid & 63;
  const int wave = tid >> 6;
  const int quad = lane >> 4, l16 = lane & 15;
  const int wm = (wave >> 1) * 64, wn = (wave & 1) * 32;
  const int bm = blockIdx.y * 128, bn = blockIdx.x * 64;

  f32x4 acc[4][2];
#pragma unroll
  for (int i = 0; i < 4; i++)
#pragma unroll
    for (int j = 0; j < 2; j++) acc[i][j] = (f32x4){0.f, 0.f, 0.f, 0.f};

#define OUT_STAGE(t, bi)                                                           \
  {                                                                                \
    const int k0s = (t) * 32;                                                      \
    char* dA = (char*)(sA + (bi) * 4096);                                          \
    char* dB = (char*)(sB + (bi) * 2048);                                          \
    _Pragma("unroll")                                                              \
    for (int k2 = 0; k2 < 2; k2++) {                                               \
      int u = k2 * 256 + tid;                                                      \
      int row = u >> 2, c4 = (u & 3) ^ (row & 3);                                  \
      GLOAD_LDS16(A + (size_t)(bm + row) * K + k0s + c4 * 8, dA + u * 16);         \
    }                                                                              \
    {                                                                              \
      int u = tid;                                                                 \
      int row = u >> 2, c4 = (u & 3) ^ (row & 3);                                  \
      GLOAD_LDS16(B + (size_t)(bn + row) * K + k0s + c4 * 8, dB + u * 16);         \
    }                                                                              \
  }

  OUT_STAGE(0, 0);
  OUT_STAGE(1, 1);

  int cur = 0, stg = 2;
  for (int T = 0; T < 32; ++T) {
    if (T < 31) asm volatile("s_waitcnt vmcnt(3)" ::: "memory");
    else        asm volatile("s_waitcnt vmcnt(0)" ::: "memory");
    __builtin_amdgcn_s_barrier();
    asm volatile("" ::: "memory");
    if (T < 30) OUT_STAGE(T + 2, stg);

    const u16* cA = sA + cur * 4096;
    const u16* cB = sB + cur * 2048;
    bf16x8 af[4], bfr[2];
#pragma unroll
    for (int mt = 0; mt < 4; mt++) {
      int ra = wm + mt * 16 + l16;
      af[mt] = *(const bf16x8*)&cA[ra * 32 + ((quad ^ (ra & 3)) * 8)];
    }
#pragma unroll
    for (int nt = 0; nt < 2; nt++) {
      int rb = wn + nt * 16 + l16;
      bfr[nt] = *(const bf16x8*)&cB[rb * 32 + ((quad ^ (rb & 3)) * 8)];
    }
#pragma unroll
    for (int mt = 0; mt < 4; mt++)
#pragma unroll
      for (int nt = 0; nt < 2; nt++)
        acc[mt][nt] = __builtin_amdgcn_mfma_f32_16x16x32_bf16(af[mt], bfr[nt], acc[mt][nt], 0, 0, 0);

    cur = (cur == 2) ? 0 : cur + 1;
    stg = (stg == 2) ? 0 : stg + 1;
  }
#undef OUT_STAGE

#pragma unroll
  for (int mt = 0; mt < 4; mt++)
#pragma unroll
    for (int nt = 0; nt < 2; nt++)
#pragma unroll
      for (int r = 0; r < 4; r++) {
        int row = bm + wm + mt * 16 + quad * 4 + r;
        int col = bn + wn + nt * 16 + l16;
        C[(size_t)row * N + col] = acc[mt][nt][r];
      }
}

// ---------------------------------------------------------------- launch
extern "C" void kernel_launch(void* const* d_in, const int* in_sizes, int n_in,
                              void* d_out, int out_size, void* d_ws, size_t ws_size,
                              hipStream_t stream) {
  const float* x  = (const float*)d_in[0];
  const float* wq = (const float*)d_in[1];
  const float* wk = (const float*)d_in[2];
  const float* wv = (const float*)d_in[3];
  const float* wo = (const float*)d_in[4];
  float* out = (float*)d_out;
  char* ws = (char*)d_ws;
  const size_t MB = 1u << 20;

  u16* xb    = (u16*)(ws);            // 8 MB  [4096 x 1024] bf16 x
  u16* wqkvb = (u16*)(ws + 8 * MB);   // 6 MB  [3072 x 1024]
  u16* wob   = (u16*)(ws + 14 * MB);  // 2 MB
  u16* QKb   = (u16*)(ws + 16 * MB);  // 16 MB [4096 x 2048] (Q*s | K)
  u16* Vtb   = (u16*)(ws + 32 * MB);  // 8 MB  [1024 hd x 4096 tok]
  u16* Ob    = xb;                    // alias: x dead after QKV gemm

  cvt_all<<<8192, 256, 0, stream>>>(x, wq, wk, wv, wo, xb, wqkvb, wob);

  gemm_qkv<<<dim3(24, 32), 256, 0, stream>>>(xb, wqkvb, QKb, Vtb);

  attn_fwd<<<512, 256, 0, stream>>>(QKb, Vtb, Ob);

  gemm_out<<<dim3(16, 32), 256, 0, stream>>>(Ob, wob, out);
}